// Round 1
// baseline (81.014 us; speedup 1.0000x reference)
//
#include <hip/hip_runtime.h>
#include <math.h>

// QuanvolutionHybrid: closed-form collapse of the quantum circuit.
// Per patch p (2x2 pixels d0..d3), per qubit k:
//   E_k = cos(beta_k)*cos(2*d_k) - cos(alpha_k)*sin(beta_k)*sin(2*d_k)
// feats[4p+0..3] = [E0, E0*E1, E2, E2*E3]
// logits = feats @ W^T + b ; out = log_softmax(logits)

__global__ __launch_bounds__(256) void quanv_kernel(
    const float* __restrict__ x,       // (4096, 784) flat
    const float* __restrict__ params,  // (8,)
    const float* __restrict__ W,       // (10, 784)
    const float* __restrict__ bias,    // (10,)
    float* __restrict__ out)           // (4096, 10)
{
    const int b = blockIdx.x;
    const int t = threadIdx.x;

    __shared__ float s_img[784];
    __shared__ float s_A[4], s_B[4];
    __shared__ float s_red[4][10];

    // Per-qubit coefficients (computed once per block by 4 threads)
    if (t < 4) {
        float al = params[2 * t];
        float be = params[2 * t + 1];
        s_A[t] = cosf(be);
        s_B[t] = sinf(be) * cosf(al);
    }

    // Coalesced image load into LDS
    const float* xb = x + (size_t)b * 784;
    for (int i = t; i < 784; i += 256) s_img[i] = xb[i];
    __syncthreads();

    float logit[10];
#pragma unroll
    for (int c = 0; c < 10; c++) logit[c] = 0.0f;

    if (t < 196) {
        const int i = t / 14;
        const int j = t - 14 * i;
        const int base = (2 * i) * 28 + 2 * j;
        const float d0 = s_img[base];
        const float d1 = s_img[base + 1];
        const float d2 = s_img[base + 28];
        const float d3 = s_img[base + 29];

        float s, c;
        sincosf(2.0f * d0, &s, &c); const float E0 = s_A[0] * c - s_B[0] * s;
        sincosf(2.0f * d1, &s, &c); const float E1 = s_A[1] * c - s_B[1] * s;
        sincosf(2.0f * d2, &s, &c); const float E2 = s_A[2] * c - s_B[2] * s;
        sincosf(2.0f * d3, &s, &c); const float E3 = s_A[3] * c - s_B[3] * s;

        const float f0 = E0;
        const float f1 = E0 * E1;
        const float f2 = E2;
        const float f3 = E2 * E3;

        const float* Wp = W + 4 * t;
#pragma unroll
        for (int c2 = 0; c2 < 10; c2++) {
            const float* wr = Wp + c2 * 784;
            logit[c2] = f0 * wr[0] + f1 * wr[1] + f2 * wr[2] + f3 * wr[3];
        }
    }

    // Wave-level reduction (64 lanes), then cross-wave via LDS
#pragma unroll
    for (int c = 0; c < 10; c++) {
        float v = logit[c];
#pragma unroll
        for (int off = 32; off > 0; off >>= 1) v += __shfl_down(v, off, 64);
        logit[c] = v;
    }
    const int wave = t >> 6;
    const int lane = t & 63;
    if (lane == 0) {
#pragma unroll
        for (int c = 0; c < 10; c++) s_red[wave][c] = logit[c];
    }
    __syncthreads();

    if (t == 0) {
        float lg[10];
        float mx = -1e30f;
#pragma unroll
        for (int c = 0; c < 10; c++) {
            lg[c] = s_red[0][c] + s_red[1][c] + s_red[2][c] + s_red[3][c] + bias[c];
            mx = fmaxf(mx, lg[c]);
        }
        float sum = 0.0f;
#pragma unroll
        for (int c = 0; c < 10; c++) sum += expf(lg[c] - mx);
        const float lse = mx + logf(sum);
        float* ob = out + (size_t)b * 10;
#pragma unroll
        for (int c = 0; c < 10; c++) ob[c] = lg[c] - lse;
    }
}

extern "C" void kernel_launch(void* const* d_in, const int* in_sizes, int n_in,
                              void* d_out, int out_size, void* d_ws, size_t ws_size,
                              hipStream_t stream) {
    const float* x      = (const float*)d_in[0];  // 4096*784
    const float* params = (const float*)d_in[1];  // 8
    const float* W      = (const float*)d_in[2];  // 10*784
    const float* bias   = (const float*)d_in[3];  // 10
    float* out          = (float*)d_out;          // 4096*10

    quanv_kernel<<<4096, 256, 0, stream>>>(x, params, W, bias, out);
}

// Round 2
// 71.220 us; speedup vs baseline: 1.1375x; 1.1375x over previous
//
#include <hip/hip_runtime.h>
#include <math.h>

// QuanvolutionHybrid: closed-form collapse of the quantum circuit.
// Per patch p (2x2 pixels d0..d3), per qubit k:
//   E_k = cos(beta_k)*cos(2*d_k) - cos(alpha_k)*sin(beta_k)*sin(2*d_k)
// feats[4p+0..3] = [E0, E0*E1, E2, E2*E3]
// logits = feats @ W^T + b ; out = log_softmax(logits)
//
// Structure: one wave (64 lanes) per image; 4 images per 256-thread block.
// Lane l handles patches l, l+64, l+128; wave butterfly-reduce 10 logits.
// Fast trig (__sinf/__cosf -> v_sin/v_cos): inputs in [0,2) rad, err ~1e-6
// vs threshold 8.1e-2.

__global__ __launch_bounds__(256) void quanv_kernel(
    const float* __restrict__ x,       // (4096, 784) flat
    const float* __restrict__ params,  // (8,)
    const float* __restrict__ W,       // (10, 784)
    const float* __restrict__ bias,    // (10,)
    float* __restrict__ out)           // (4096, 10)
{
    const int t = threadIdx.x;
    const int wave = t >> 6;
    const int lane = t & 63;
    const int b = blockIdx.x * 4 + wave;   // image index

    __shared__ float s_img[4][784];

    // Coalesced staging: 4 images = 784 float4 per block
    {
        const float4* src = (const float4*)(x + (size_t)blockIdx.x * 4 * 784);
        float4* dst = (float4*)(&s_img[0][0]);
        for (int i = t; i < 784; i += 256) dst[i] = src[i];
    }

    // Per-qubit coefficients, every lane computes (uniform -> scalarized)
    float A[4], Bc[4];
#pragma unroll
    for (int k = 0; k < 4; k++) {
        const float al = params[2 * k];
        const float be = params[2 * k + 1];
        A[k]  = __cosf(be);
        Bc[k] = __sinf(be) * __cosf(al);
    }

    __syncthreads();

    float lg[10];
#pragma unroll
    for (int c = 0; c < 10; c++) lg[c] = 0.0f;

    const float* img = s_img[wave];
    const float4* W4 = (const float4*)W;   // [c][196] float4 rows

    for (int p = lane; p < 196; p += 64) {
        const int i = p / 14;
        const int j = p - 14 * i;
        const int base = i * 56 + 2 * j;
        const float d0 = img[base];
        const float d1 = img[base + 1];
        const float d2 = img[base + 28];
        const float d3 = img[base + 29];

        const float E0 = A[0] * __cosf(2.0f * d0) - Bc[0] * __sinf(2.0f * d0);
        const float E1 = A[1] * __cosf(2.0f * d1) - Bc[1] * __sinf(2.0f * d1);
        const float E2 = A[2] * __cosf(2.0f * d2) - Bc[2] * __sinf(2.0f * d2);
        const float E3 = A[3] * __cosf(2.0f * d3) - Bc[3] * __sinf(2.0f * d3);

        const float f0 = E0;
        const float f1 = E0 * E1;
        const float f2 = E2;
        const float f3 = E2 * E3;

#pragma unroll
        for (int c = 0; c < 10; c++) {
            const float4 w = W4[c * 196 + p];
            lg[c] += f0 * w.x + f1 * w.y + f2 * w.z + f3 * w.w;
        }
    }

    // Wave butterfly reduction of 10 logits (result valid in lane 0)
#pragma unroll
    for (int c = 0; c < 10; c++) {
        float v = lg[c];
#pragma unroll
        for (int off = 32; off > 0; off >>= 1) v += __shfl_down(v, off, 64);
        lg[c] = v;
    }

    if (lane == 0) {
        float mx = -1e30f;
#pragma unroll
        for (int c = 0; c < 10; c++) {
            lg[c] += bias[c];
            mx = fmaxf(mx, lg[c]);
        }
        float sum = 0.0f;
#pragma unroll
        for (int c = 0; c < 10; c++) sum += __expf(lg[c] - mx);
        const float lse = mx + __logf(sum);
        float* ob = out + (size_t)b * 10;
#pragma unroll
        for (int c = 0; c < 10; c++) ob[c] = lg[c] - lse;
    }
}

extern "C" void kernel_launch(void* const* d_in, const int* in_sizes, int n_in,
                              void* d_out, int out_size, void* d_ws, size_t ws_size,
                              hipStream_t stream) {
    const float* x      = (const float*)d_in[0];  // 4096*784
    const float* params = (const float*)d_in[1];  // 8
    const float* W      = (const float*)d_in[2];  // 10*784
    const float* bias   = (const float*)d_in[3];  // 10
    float* out          = (float*)d_out;          // 4096*10

    quanv_kernel<<<1024, 256, 0, stream>>>(x, params, W, bias, out);
}

// Round 3
// 70.974 us; speedup vs baseline: 1.1415x; 1.0035x over previous
//
#include <hip/hip_runtime.h>
#include <math.h>

// QuanvolutionHybrid: closed-form collapse of the quantum circuit.
// Per patch p (2x2 pixels d0..d3), per qubit k:
//   E_k = cos(beta_k)*cos(2*d_k) - cos(alpha_k)*sin(beta_k)*sin(2*d_k)
// feats[4p+0..3] = [E0, E0*E1, E2, E2*E3]
// logits = feats @ W^T + b ; out = log_softmax(logits)
//
// One wave (64 lanes) per image, 4 independent waves per block, NO LDS, NO
// barrier: patches are non-overlapping so each lane loads its own patch
// directly as two float2 (contiguous across lanes in 14-lane groups; all
// bytes consumed within the wave -> HBM traffic unchanged at 12.8 MB).
// Ragged tail (196 = 3*64 + 4) handled by clamp+mask: uniform control flow.

__global__ __launch_bounds__(256) void quanv_kernel(
    const float* __restrict__ x,       // (4096, 784) flat
    const float* __restrict__ params,  // (8,)
    const float* __restrict__ W,       // (10, 784)
    const float* __restrict__ bias,    // (10,)
    float* __restrict__ out)           // (4096, 10)
{
    const int t = threadIdx.x;
    const int wave = t >> 6;
    const int lane = t & 63;
    const int b = blockIdx.x * 4 + wave;   // image index

    // Per-qubit coefficients (lane-uniform -> scalarized by compiler)
    float A[4], Bc[4];
#pragma unroll
    for (int k = 0; k < 4; k++) {
        const float al = params[2 * k];
        const float be = params[2 * k + 1];
        A[k]  = __cosf(be);
        Bc[k] = __sinf(be) * __cosf(al);
    }

    const float* img = x + (size_t)b * 784;
    const float4* W4 = (const float4*)W;   // [c][196] float4 rows

    float lg[10];
#pragma unroll
    for (int c = 0; c < 10; c++) lg[c] = 0.0f;

#pragma unroll
    for (int k = 0; k < 4; k++) {
        const int praw = lane + 64 * k;
        const bool valid = (praw < 196);
        const int p = valid ? praw : 195;          // clamp: keeps loads in-bounds
        const int i = p / 14;
        const int j = p - 14 * i;

        const float2 d01 = *(const float2*)(img + i * 56 + 2 * j);
        const float2 d23 = *(const float2*)(img + i * 56 + 28 + 2 * j);

        const float E0 = A[0] * __cosf(2.0f * d01.x) - Bc[0] * __sinf(2.0f * d01.x);
        const float E1 = A[1] * __cosf(2.0f * d01.y) - Bc[1] * __sinf(2.0f * d01.y);
        const float E2 = A[2] * __cosf(2.0f * d23.x) - Bc[2] * __sinf(2.0f * d23.x);
        const float E3 = A[3] * __cosf(2.0f * d23.y) - Bc[3] * __sinf(2.0f * d23.y);

        float f0 = E0;
        float f1 = E0 * E1;
        float f2 = E2;
        float f3 = E2 * E3;
        if (!valid) { f0 = 0.0f; f1 = 0.0f; f2 = 0.0f; f3 = 0.0f; }

#pragma unroll
        for (int c = 0; c < 10; c++) {
            const float4 w = W4[c * 196 + p];
            lg[c] += f0 * w.x + f1 * w.y + f2 * w.z + f3 * w.w;
        }
    }

    // Wave butterfly reduction of 10 logits (result valid in lane 0);
    // 10 independent dependency chains -> pipelined bpermutes.
#pragma unroll
    for (int c = 0; c < 10; c++) {
        float v = lg[c];
#pragma unroll
        for (int off = 32; off > 0; off >>= 1) v += __shfl_down(v, off, 64);
        lg[c] = v;
    }

    if (lane == 0) {
        float mx = -1e30f;
#pragma unroll
        for (int c = 0; c < 10; c++) {
            lg[c] += bias[c];
            mx = fmaxf(mx, lg[c]);
        }
        float sum = 0.0f;
#pragma unroll
        for (int c = 0; c < 10; c++) sum += __expf(lg[c] - mx);
        const float lse = mx + __logf(sum);
        float* ob = out + (size_t)b * 10;
#pragma unroll
        for (int c = 0; c < 10; c++) ob[c] = lg[c] - lse;
    }
}

extern "C" void kernel_launch(void* const* d_in, const int* in_sizes, int n_in,
                              void* d_out, int out_size, void* d_ws, size_t ws_size,
                              hipStream_t stream) {
    const float* x      = (const float*)d_in[0];  // 4096*784
    const float* params = (const float*)d_in[1];  // 8
    const float* W      = (const float*)d_in[2];  // 10*784
    const float* bias   = (const float*)d_in[3];  // 10
    float* out          = (float*)d_out;          // 4096*10

    quanv_kernel<<<1024, 256, 0, stream>>>(x, params, W, bias, out);
}